// Round 3
// baseline (554.951 us; speedup 1.0000x reference)
//
#include <hip/hip_runtime.h>
#include <hip/hip_bf16.h>
#include <math.h>

#define N_NODES 50000
#define N_EDGES 800000
#define NRAD 20
#define NBLK 196   // ceil(50000/256)

__device__ __forceinline__ unsigned short f2b(float f) {
    union { __hip_bfloat16 h; unsigned short u; } cv;
    cv.h = __float2bfloat16(f);
    return cv.u;
}
__device__ __forceinline__ float pack2bf(float a, float b) {
    unsigned int u = (unsigned int)f2b(a) | ((unsigned int)f2b(b) << 16);
    return __uint_as_float(u);
}

__global__ void zero_counts_kernel(int* __restrict__ counts) {
    int i = blockIdx.x * blockDim.x + threadIdx.x;
    if (i < N_NODES) counts[i] = 0;
}

// Thread-per-node MLP; weights lane-uniform -> scalar loads. Output stored bf16.
__global__ __launch_bounds__(128) void node_mlp_kernel(
    const float* __restrict__ ns, const float* __restrict__ W1, const float* __restrict__ b1,
    const float* __restrict__ W2, const float* __restrict__ b2,
    unsigned short* __restrict__ sob) {
    __shared__ float XT[64 * 133];
    __shared__ float HT[64 * 133];
    int t = threadIdx.x;
    int base = blockIdx.x * 128;
    int nb = min(128, N_NODES - base);

    int total4 = nb * 16;
    const float4* xsrc = (const float4*)(ns + (size_t)base * 64);
    for (int q = t; q < total4; q += 128) {
        float4 v = xsrc[q];
        int node = q >> 4;
        int k = (q & 15) * 4;
        XT[(k + 0) * 133 + node] = v.x;
        XT[(k + 1) * 133 + node] = v.y;
        XT[(k + 2) * 133 + node] = v.z;
        XT[(k + 3) * 133 + node] = v.w;
    }
    __syncthreads();

    bool act = t < nb;
    float h[64];
#pragma unroll
    for (int c = 0; c < 64; c++) h[c] = b1[c];
    if (act) {
        for (int k = 0; k < 64; k++) {
            float xk = XT[k * 133 + t];
            const float* wr = W1 + k * 64;
#pragma unroll
            for (int c = 0; c < 64; c++) h[c] = fmaf(xk, wr[c], h[c]);
        }
#pragma unroll
        for (int c = 0; c < 64; c++) {
            float v = h[c];
            v = v / (1.0f + __expf(-v));
            HT[c * 133 + t] = v;
        }
    }
    __syncthreads();

    if (act) {
        size_t ob = (size_t)(base + t) * 192;
        for (int ch = 0; ch < 3; ch++) {
            float o[64];
#pragma unroll
            for (int c = 0; c < 64; c++) o[c] = b2[ch * 64 + c];
            for (int k = 0; k < 64; k++) {
                float hk = HT[k * 133 + t];
                const float* wr = W2 + k * 192 + ch * 64;
#pragma unroll
                for (int c = 0; c < 64; c++) o[c] = fmaf(hk, wr[c], o[c]);
            }
            unsigned int* dst = (unsigned int*)(sob + ob + ch * 64);
#pragma unroll
            for (int c = 0; c < 32; c++)
                dst[c] = (unsigned int)f2b(o[2 * c]) | ((unsigned int)f2b(o[2 * c + 1]) << 16);
        }
    }
}

// nv (N,3,64) f32 -> bf16, coalesced
__global__ __launch_bounds__(256) void nv_convert_kernel(const float* __restrict__ nv,
                                                         unsigned short* __restrict__ nvb) {
    int i = blockIdx.x * blockDim.x + threadIdx.x;  // over float4s: 2.4M
    const float4* src = (const float4*)nv;
    float4 v = src[i];
    unsigned int* dst = (unsigned int*)nvb;
    dst[2 * i]     = (unsigned int)f2b(v.x) | ((unsigned int)f2b(v.y) << 16);
    dst[2 * i + 1] = (unsigned int)f2b(v.z) | ((unsigned int)f2b(v.w) << 16);
}

__global__ void hist_kernel(const int* __restrict__ edge, int* __restrict__ counts) {
    int e = blockIdx.x * blockDim.x + threadIdx.x;
    if (e < N_EDGES) atomicAdd(&counts[edge[2 * e]], 1);
}

__global__ __launch_bounds__(256) void scan_part1(const int* __restrict__ counts,
                                                  int* __restrict__ bsum) {
    __shared__ int red[256];
    int t = threadIdx.x, i = blockIdx.x * 256 + t;
    red[t] = (i < N_NODES) ? counts[i] : 0;
    __syncthreads();
    for (int s = 128; s > 0; s >>= 1) {
        if (t < s) red[t] += red[t + s];
        __syncthreads();
    }
    if (t == 0) bsum[blockIdx.x] = red[0];
}

__global__ __launch_bounds__(256) void scan_part2(const int* __restrict__ bsum,
                                                  int* __restrict__ boff) {
    __shared__ int s[256];
    int t = threadIdx.x;
    s[t] = (t < NBLK) ? bsum[t] : 0;
    __syncthreads();
    for (int off = 1; off < 256; off <<= 1) {
        int v = (t >= off) ? s[t - off] : 0;
        __syncthreads();
        s[t] += v;
        __syncthreads();
    }
    boff[t] = (t == 0) ? 0 : s[t - 1];
}

__global__ __launch_bounds__(256) void scan_part3(const int* __restrict__ counts,
                                                  const int* __restrict__ boff,
                                                  int* __restrict__ offs,
                                                  int* __restrict__ cursors) {
    __shared__ int s[256];
    int t = threadIdx.x, b = blockIdx.x, i = b * 256 + t;
    int v = (i < N_NODES) ? counts[i] : 0;
    s[t] = v;
    __syncthreads();
    for (int off = 1; off < 256; off <<= 1) {
        int u = (t >= off) ? s[t - off] : 0;
        __syncthreads();
        s[t] += u;
        __syncthreads();
    }
    int excl = s[t] - v + boff[b];
    if (i < N_NODES) {
        offs[i] = excl;
        cursors[i] = excl;
    }
    if (i == N_NODES - 1) offs[N_NODES] = excl + v;
}

// Bucket + per-edge scalar precompute (computed ONCE per edge, not x64 lanes).
// struct per edge (4 float4 = 64B), dst-sorted:
//  q0 = {srcbits, cut, u0, u1}
//  q1 = {u2, rp0, rp1, rp2}    rp_j = bf16pair(r[2j], r[2j+1]), r_k = sin((k+1)x)*inv*cut
//  q2 = {rp3, rp4, rp5, rp6}
//  q3 = {rp7, rp8, rp9, 0}
__global__ __launch_bounds__(256) void bucket_kernel(
    const int* __restrict__ edge, const float* __restrict__ ediff,
    const float* __restrict__ edist, int* __restrict__ cursors,
    float4* __restrict__ pack) {
    int e = blockIdx.x * blockDim.x + threadIdx.x;
    if (e >= N_EDGES) return;
    int dst = edge[2 * e];
    int src = edge[2 * e + 1];
    int pos = atomicAdd(&cursors[dst], 1);

    float dist = edist[e];
    float d0 = ediff[3 * e], d1 = ediff[3 * e + 1], d2 = ediff[3 * e + 2];
    float inv = __builtin_amdgcn_rcpf(dist);
    float x = dist * (3.14159265358979323846f / 5.0f);
    float s1 = __sinf(x);
    float c1 = __cosf(x);
    float cut = (dist < 5.0f) ? 0.5f * (c1 + 1.0f) : 0.0f;
    float ic = inv * cut;
    float t2 = 2.0f * c1;
    float r[NRAD];
    float sn = s1, sp = 0.0f;
#pragma unroll
    for (int k = 0; k < NRAD; k++) {
        r[k] = sn * ic;
        float nx = t2 * sn - sp;
        sp = sn;
        sn = nx;
    }
    float rp[10];
#pragma unroll
    for (int j = 0; j < 10; j++) rp[j] = pack2bf(r[2 * j], r[2 * j + 1]);

    float4* P = pack + (size_t)pos * 4;
    P[0] = make_float4(__int_as_float(src), cut, d0 * inv, d1 * inv);
    P[1] = make_float4(d2 * inv, rp[0], rp[1], rp[2]);
    P[2] = make_float4(rp[3], rp[4], rp[5], rp[6]);
    P[3] = make_float4(rp[7], rp[8], rp[9], 0.0f);
}

__device__ __forceinline__ float blo(float p) {
    return __uint_as_float(__float_as_uint(p) << 16);
}
__device__ __forceinline__ float bhi(float p) {
    return __uint_as_float(__float_as_uint(p) & 0xffff0000u);
}
__device__ __forceinline__ float bup(unsigned short u) {
    return __uint_as_float(((unsigned int)u) << 16);
}

// One wave per destination node; broadcast struct loads + bf16 gathers.
__global__ __launch_bounds__(256) void gather_kernel(
    const float* __restrict__ ns, const float* __restrict__ nv,
    const float* __restrict__ Wf, const float* __restrict__ bfv,
    const unsigned short* __restrict__ sob, const unsigned short* __restrict__ nvb,
    const int* __restrict__ offs, const float4* __restrict__ pack,
    float* __restrict__ out0, float* __restrict__ out1) {
    int t = threadIdx.x;
    int l = t & 63;
    int n = (blockIdx.x * 256 + t) >> 6;

    float wf0[NRAD], wf1[NRAD], wf2[NRAD];
#pragma unroll
    for (int k = 0; k < NRAD; k++) {
        wf0[k] = Wf[k * 192 + l];
        wf1[k] = Wf[k * 192 + 64 + l];
        wf2[k] = Wf[k * 192 + 128 + l];
    }
    float bf0 = bfv[l], bf1 = bfv[64 + l], bf2 = bfv[128 + l];
    if (n >= N_NODES) return;

    int start = offs[n], end = offs[n + 1];
    float acc_s = 0.0f, a0 = 0.0f, a1 = 0.0f, a2 = 0.0f;

    for (int i = start; i < end; i++) {
        const float4* P = pack + (size_t)i * 4;
        float4 q0 = P[0];
        float4 q1 = P[1];
        float4 q2 = P[2];
        float4 q3 = P[3];
        int src = __float_as_int(q0.x);
        float cut = q0.y;
        float u0 = q0.z, u1 = q0.w, u2 = q1.x;
        float r[NRAD];
        r[0] = blo(q1.y); r[1] = bhi(q1.y);
        r[2] = blo(q1.z); r[3] = bhi(q1.z);
        r[4] = blo(q1.w); r[5] = bhi(q1.w);
        r[6] = blo(q2.x); r[7] = bhi(q2.x);
        r[8] = blo(q2.y); r[9] = bhi(q2.y);
        r[10] = blo(q2.z); r[11] = bhi(q2.z);
        r[12] = blo(q2.w); r[13] = bhi(q2.w);
        r[14] = blo(q3.x); r[15] = bhi(q3.x);
        r[16] = blo(q3.y); r[17] = bhi(q3.y);
        r[18] = blo(q3.z); r[19] = bhi(q3.z);

        float f0 = bf0 * cut, f1 = bf1 * cut, f2 = bf2 * cut;
#pragma unroll
        for (int k = 0; k < NRAD; k++) {
            f0 = fmaf(r[k], wf0[k], f0);
            f1 = fmaf(r[k], wf1[k], f1);
            f2 = fmaf(r[k], wf2[k], f2);
        }

        size_t sb = (size_t)src * 192;
        float s0 = bup(sob[sb + l]);
        float s1v = bup(sob[sb + 64 + l]);
        float s2 = bup(sob[sb + 128 + l]);
        float v0 = bup(nvb[sb + l]);
        float v1 = bup(nvb[sb + 64 + l]);
        float v2 = bup(nvb[sb + 128 + l]);

        float g0 = f0 * s0;
        float g1 = f1 * s1v;
        float ms = f2 * s2;
        acc_s += ms;
        a0 += fmaf(v0, g0, g1 * u0);
        a1 += fmaf(v1, g0, g1 * u1);
        a2 += fmaf(v2, g0, g1 * u2);
    }

    size_t b64 = (size_t)n * 64, b192 = (size_t)n * 192;
    out0[b64 + l] = ns[b64 + l] + acc_s;
    out1[b192 + l] = nv[b192 + l] + a0;
    out1[b192 + 64 + l] = nv[b192 + 64 + l] + a1;
    out1[b192 + 128 + l] = nv[b192 + 128 + l] + a2;
}

extern "C" void kernel_launch(void* const* d_in, const int* in_sizes, int n_in,
                              void* d_out, int out_size, void* d_ws, size_t ws_size,
                              hipStream_t stream) {
    const float* ns    = (const float*)d_in[0];
    const float* nv    = (const float*)d_in[1];
    const int*   edge  = (const int*)d_in[2];
    const float* ediff = (const float*)d_in[3];
    const float* edist = (const float*)d_in[4];
    const float* W1    = (const float*)d_in[5];
    const float* b1    = (const float*)d_in[6];
    const float* W2    = (const float*)d_in[7];
    const float* b2    = (const float*)d_in[8];
    const float* Wf    = (const float*)d_in[9];
    const float* bfv   = (const float*)d_in[10];

    float* out0 = (float*)d_out;
    float* out1 = out0 + (size_t)N_NODES * 64;

    // workspace: pack (E*64B) | sob (N*192*2B) | nvb (N*192*2B) | int arrays
    char* w = (char*)d_ws;
    float4* pack = (float4*)w;                     w += (size_t)N_EDGES * 64;
    unsigned short* sob = (unsigned short*)w;      w += (size_t)N_NODES * 192 * 2;
    unsigned short* nvb = (unsigned short*)w;      w += (size_t)N_NODES * 192 * 2;
    int* counts  = (int*)w;
    int* offs    = counts + N_NODES;
    int* cursors = offs + (N_NODES + 1);
    int* bsum    = cursors + N_NODES;
    int* boff    = bsum + 256;

    zero_counts_kernel<<<(N_NODES + 255) / 256, 256, 0, stream>>>(counts);
    node_mlp_kernel<<<(N_NODES + 127) / 128, 128, 0, stream>>>(ns, W1, b1, W2, b2, sob);
    nv_convert_kernel<<<(N_NODES * 192 / 4 + 255) / 256, 256, 0, stream>>>(nv, nvb);
    hist_kernel<<<(N_EDGES + 255) / 256, 256, 0, stream>>>(edge, counts);
    scan_part1<<<NBLK, 256, 0, stream>>>(counts, bsum);
    scan_part2<<<1, 256, 0, stream>>>(bsum, boff);
    scan_part3<<<NBLK, 256, 0, stream>>>(counts, boff, offs, cursors);
    bucket_kernel<<<(N_EDGES + 255) / 256, 256, 0, stream>>>(edge, ediff, edist, cursors, pack);
    gather_kernel<<<N_NODES / 4, 256, 0, stream>>>(ns, nv, Wf, bfv, sob, nvb,
                                                   offs, pack, out0, out1);
}

// Round 4
// 435.458 us; speedup vs baseline: 1.2744x; 1.2744x over previous
//
#include <hip/hip_runtime.h>
#include <hip/hip_bf16.h>
#include <math.h>

#define N_NODES 50000
#define N_EDGES 800000
#define NRAD 20
#define NBLK 196   // ceil(50000/256)

typedef short bf16x8 __attribute__((ext_vector_type(8)));
typedef float f32x4 __attribute__((ext_vector_type(4)));
typedef _Float16 half2v __attribute__((ext_vector_type(2)));

__device__ __forceinline__ unsigned short f2b(float f) {
    union { __hip_bfloat16 h; unsigned short u; } cv;
    cv.h = __float2bfloat16(f);
    return cv.u;
}
__device__ __forceinline__ unsigned int packh2(float a, float b) {
    union { _Float16 h; unsigned short u; } A, B;
    A.h = (_Float16)a; B.h = (_Float16)b;
    return (unsigned int)A.u | ((unsigned int)B.u << 16);
}
__device__ __forceinline__ half2v ash2(float f) {
    union { float f; half2v h; } u; u.f = f; return u.h;
}
__device__ __forceinline__ half2v ash2u(unsigned int x) {
    union { unsigned int u; half2v h; } u; u.u = x; return u.h;
}
__device__ __forceinline__ float bup(unsigned short u) {
    return __uint_as_float(((unsigned int)u) << 16);
}
__device__ __forceinline__ f32x4 mfma16(bf16x8 a, bf16x8 b, f32x4 c) {
    return __builtin_amdgcn_mfma_f32_16x16x32_bf16(a, b, c, 0, 0, 0);
}

// Pre-transpose weights to [n][k] bf16 (B-operand wants 8 contiguous K per lane),
// pack Wf columns as f16 pairs for v_dot2.
__global__ __launch_bounds__(256) void wprep_kernel(
    const float* __restrict__ W1, const float* __restrict__ W2, const float* __restrict__ Wf,
    unsigned short* __restrict__ W1t, unsigned short* __restrict__ W2t,
    unsigned int* __restrict__ Wfp) {
    int i = blockIdx.x * 256 + threadIdx.x;
    if (i < 64 * 64) { int n = i >> 6, k = i & 63; W1t[i] = f2b(W1[k * 64 + n]); }
    if (i < 192 * 64) { int n = i >> 6, k = i & 63; W2t[i] = f2b(W2[k * 192 + n]); }
    if (i < 3 * 10 * 64) {
        int ch = i / 640, rem = i % 640, j = rem >> 6, l = rem & 63;
        Wfp[i] = packh2(Wf[(2 * j) * 192 + ch * 64 + l],
                        Wf[(2 * j + 1) * 192 + ch * 64 + l]);
    }
}

// nv f32 -> bf16 into interleaved per-node array snb[n][384] (sob 0:192 | nvb 192:384).
// Also zeroes counts (ordering safe: hist launches later on same stream).
__global__ __launch_bounds__(256) void nv_convert_kernel(const float* __restrict__ nv,
        unsigned short* __restrict__ snb, int* __restrict__ counts) {
    int i = blockIdx.x * 256 + threadIdx.x;
    if (i < N_NODES) counts[i] = 0;
    if (i >= N_NODES * 192 / 4) return;
    float4 v = ((const float4*)nv)[i];
    int e = i * 4;
    int n = (unsigned)e / 192u;
    int r = e - n * 192;
    uint2 pk;
    pk.x = (unsigned int)f2b(v.x) | ((unsigned int)f2b(v.y) << 16);
    pk.y = (unsigned int)f2b(v.z) | ((unsigned int)f2b(v.w) << 16);
    *(uint2*)(snb + (size_t)n * 384 + 192 + r) = pk;
}

// MFMA MLP: block = 256 thr = 4 waves, 64 nodes. Wave w owns rows [16w,16w+16).
// A-frag: A[m=lane&15][k=quad*8+j]; C/D: row=quad*4+reg, col=lane&15.
__global__ __launch_bounds__(256) void node_mlp_kernel(
    const float* __restrict__ ns, const unsigned short* __restrict__ W1t,
    const float* __restrict__ b1, const unsigned short* __restrict__ W2t,
    const float* __restrict__ b2, unsigned short* __restrict__ snb) {
    __shared__ unsigned short H[64 * 72];   // pad 72 -> 2-way (free) b128 reads
    __shared__ unsigned short O[64 * 200];
    int t = threadIdx.x;
    int lane = t & 63;
    int w = t >> 6;
    int c15 = lane & 15;
    int quad = lane >> 4;
    int base = blockIdx.x * 64;

    int node = base + 16 * w + c15;
    if (node >= N_NODES) node = N_NODES - 1;

    // Layer 1 A-fragments direct from global, f32->bf16
    bf16x8 a0, a1;
    {
        const float* xr = ns + (size_t)node * 64 + quad * 8;
        float4 p0 = *(const float4*)xr;
        float4 p1 = *(const float4*)(xr + 4);
        float4 p2 = *(const float4*)(xr + 32);
        float4 p3 = *(const float4*)(xr + 36);
        a0[0] = (short)f2b(p0.x); a0[1] = (short)f2b(p0.y);
        a0[2] = (short)f2b(p0.z); a0[3] = (short)f2b(p0.w);
        a0[4] = (short)f2b(p1.x); a0[5] = (short)f2b(p1.y);
        a0[6] = (short)f2b(p1.z); a0[7] = (short)f2b(p1.w);
        a1[0] = (short)f2b(p2.x); a1[1] = (short)f2b(p2.y);
        a1[2] = (short)f2b(p2.z); a1[3] = (short)f2b(p2.w);
        a1[4] = (short)f2b(p3.x); a1[5] = (short)f2b(p3.y);
        a1[6] = (short)f2b(p3.z); a1[7] = (short)f2b(p3.w);
    }

    // Layer 1: h = silu(x@W1 + b1) -> H (LDS, bf16, A-layout friendly row-major)
#pragma unroll
    for (int nt = 0; nt < 4; nt++) {
        float bc = b1[nt * 16 + c15];
        f32x4 acc = {bc, bc, bc, bc};
        bf16x8 w0 = *(const bf16x8*)(W1t + (nt * 16 + c15) * 64 + quad * 8);
        bf16x8 w1 = *(const bf16x8*)(W1t + (nt * 16 + c15) * 64 + 32 + quad * 8);
        acc = mfma16(a0, w0, acc);
        acc = mfma16(a1, w1, acc);
#pragma unroll
        for (int r = 0; r < 4; r++) {
            float v = acc[r];
            v = v / (1.0f + __expf(-v));  // silu
            H[(16 * w + quad * 4 + r) * 72 + nt * 16 + c15] = f2b(v);
        }
    }

    // No barrier: each wave reads only its own 16 rows (same-wave LDS ordering).
    bf16x8 h0 = *(const bf16x8*)(H + (16 * w + c15) * 72 + quad * 8);
    bf16x8 h1 = *(const bf16x8*)(H + (16 * w + c15) * 72 + 32 + quad * 8);

    // Layer 2: o = h@W2 + b2 -> O (LDS) for coalesced copy-out
#pragma unroll
    for (int nt = 0; nt < 12; nt++) {
        float bc = b2[nt * 16 + c15];
        f32x4 acc = {bc, bc, bc, bc};
        bf16x8 w0 = *(const bf16x8*)(W2t + (nt * 16 + c15) * 64 + quad * 8);
        bf16x8 w1 = *(const bf16x8*)(W2t + (nt * 16 + c15) * 64 + 32 + quad * 8);
        acc = mfma16(h0, w0, acc);
        acc = mfma16(h1, w1, acc);
#pragma unroll
        for (int r = 0; r < 4; r++)
            O[(16 * w + quad * 4 + r) * 200 + nt * 16 + c15] = f2b(acc[r]);
    }
    __syncthreads();

    int nb = min(64, N_NODES - base);
    for (int idx = t; idx < nb * 24; idx += 256) {
        int row = idx / 24, seg = idx - row * 24;
        uint4 v = *(const uint4*)((const unsigned short*)O + row * 200 + seg * 8);
        *(uint4*)(snb + (size_t)(base + row) * 384 + seg * 8) = v;
    }
}

__global__ void hist_kernel(const int* __restrict__ edge, int* __restrict__ counts) {
    int e = blockIdx.x * blockDim.x + threadIdx.x;
    if (e < N_EDGES) atomicAdd(&counts[edge[2 * e]], 1);
}

__global__ __launch_bounds__(256) void scan_part1(const int* __restrict__ counts,
                                                  int* __restrict__ bsum) {
    __shared__ int red[256];
    int t = threadIdx.x, i = blockIdx.x * 256 + t;
    red[t] = (i < N_NODES) ? counts[i] : 0;
    __syncthreads();
    for (int s = 128; s > 0; s >>= 1) {
        if (t < s) red[t] += red[t + s];
        __syncthreads();
    }
    if (t == 0) bsum[blockIdx.x] = red[0];
}

__global__ __launch_bounds__(256) void scan_part2(const int* __restrict__ bsum,
                                                  int* __restrict__ boff) {
    __shared__ int s[256];
    int t = threadIdx.x;
    s[t] = (t < NBLK) ? bsum[t] : 0;
    __syncthreads();
    for (int off = 1; off < 256; off <<= 1) {
        int v = (t >= off) ? s[t - off] : 0;
        __syncthreads();
        s[t] += v;
        __syncthreads();
    }
    boff[t] = (t == 0) ? 0 : s[t - 1];
}

__global__ __launch_bounds__(256) void scan_part3(const int* __restrict__ counts,
                                                  const int* __restrict__ boff,
                                                  int* __restrict__ offs,
                                                  int* __restrict__ cursors) {
    __shared__ int s[256];
    int t = threadIdx.x, b = blockIdx.x, i = b * 256 + t;
    int v = (i < N_NODES) ? counts[i] : 0;
    s[t] = v;
    __syncthreads();
    for (int off = 1; off < 256; off <<= 1) {
        int u = (t >= off) ? s[t - off] : 0;
        __syncthreads();
        s[t] += u;
        __syncthreads();
    }
    int excl = s[t] - v + boff[b];
    if (i < N_NODES) {
        offs[i] = excl;
        cursors[i] = excl;
    }
    if (i == N_NODES - 1) offs[N_NODES] = excl + v;
}

// Bucket + per-edge scalar precompute. 64B struct, dst-sorted:
//  q0 = {srcbits, cut, u0, u1}
//  q1 = {u2, rp0..rp2}   rp_j = f16pair(r[2j], r[2j+1]), r_k = sin((k+1)x)*inv*cut
//  q2 = {rp3..rp6}
//  q3 = {rp7..rp9, 0}
__global__ __launch_bounds__(256) void bucket_kernel(
    const int* __restrict__ edge, const float* __restrict__ ediff,
    const float* __restrict__ edist, int* __restrict__ cursors,
    float4* __restrict__ pack) {
    int e = blockIdx.x * blockDim.x + threadIdx.x;
    if (e >= N_EDGES) return;
    int dst = edge[2 * e];
    int src = edge[2 * e + 1];
    int pos = atomicAdd(&cursors[dst], 1);

    float dist = edist[e];
    float d0 = ediff[3 * e], d1 = ediff[3 * e + 1], d2 = ediff[3 * e + 2];
    float inv = __builtin_amdgcn_rcpf(dist);
    float x = dist * (3.14159265358979323846f / 5.0f);
    float s1 = __sinf(x);
    float c1 = __cosf(x);
    float cut = (dist < 5.0f) ? 0.5f * (c1 + 1.0f) : 0.0f;
    float ic = inv * cut;
    float t2 = 2.0f * c1;
    float r[NRAD];
    float sn = s1, sp = 0.0f;
#pragma unroll
    for (int k = 0; k < NRAD; k++) {
        r[k] = sn * ic;
        float nx = t2 * sn - sp;
        sp = sn;
        sn = nx;
    }
    unsigned int rp[10];
#pragma unroll
    for (int j = 0; j < 10; j++) rp[j] = packh2(r[2 * j], r[2 * j + 1]);

    float4* P = pack + (size_t)pos * 4;
    P[0] = make_float4(__int_as_float(src), cut, d0 * inv, d1 * inv);
    P[1] = make_float4(d2 * inv, __uint_as_float(rp[0]), __uint_as_float(rp[1]),
                       __uint_as_float(rp[2]));
    P[2] = make_float4(__uint_as_float(rp[3]), __uint_as_float(rp[4]),
                       __uint_as_float(rp[5]), __uint_as_float(rp[6]));
    P[3] = make_float4(__uint_as_float(rp[7]), __uint_as_float(rp[8]),
                       __uint_as_float(rp[9]), 0.0f);
}

// One wave per destination node; depth-2 pipelined; filter dot via v_dot2_f32_f16.
__global__ __launch_bounds__(256) void gather_kernel(
    const float* __restrict__ ns, const float* __restrict__ nv,
    const unsigned int* __restrict__ Wfp, const float* __restrict__ bfv,
    const unsigned short* __restrict__ snb,
    const int* __restrict__ offs, const float4* __restrict__ pack,
    float* __restrict__ out0, float* __restrict__ out1) {
    int t = threadIdx.x;
    int l = t & 63;
    int n = (blockIdx.x * 256 + t) >> 6;

    half2v wf0[10], wf1[10], wf2[10];
#pragma unroll
    for (int j = 0; j < 10; j++) {
        wf0[j] = ash2u(Wfp[j * 64 + l]);
        wf1[j] = ash2u(Wfp[640 + j * 64 + l]);
        wf2[j] = ash2u(Wfp[1280 + j * 64 + l]);
    }
    float bf0 = bfv[l], bf1 = bfv[64 + l], bf2 = bfv[128 + l];
    if (n >= N_NODES) return;

    int start = offs[n], end = offs[n + 1];
    float acc_s = 0.0f, a0 = 0.0f, a1 = 0.0f, a2 = 0.0f;

    float4 q0, q1, q2, q3;
    unsigned int g0 = 0, g1 = 0, g2 = 0, g3 = 0, g4 = 0, g5 = 0;
    if (start < end) {
        const float4* P = pack + (size_t)start * 4;
        q0 = P[0]; q1 = P[1]; q2 = P[2]; q3 = P[3];
        const unsigned short* sn = snb + (size_t)__float_as_int(q0.x) * 384;
        g0 = sn[l]; g1 = sn[64 + l]; g2 = sn[128 + l];
        g3 = sn[192 + l]; g4 = sn[256 + l]; g5 = sn[320 + l];
    }
    for (int i = start; i < end; i++) {
        float4 c0 = q0, c1 = q1, c2 = q2, c3 = q3;
        unsigned int h0 = g0, h1 = g1, h2 = g2, h3 = g3, h4 = g4, h5 = g5;
        if (i + 1 < end) {
            const float4* P = pack + (size_t)(i + 1) * 4;
            q0 = P[0]; q1 = P[1]; q2 = P[2]; q3 = P[3];
            const unsigned short* sn = snb + (size_t)__float_as_int(q0.x) * 384;
            g0 = sn[l]; g1 = sn[64 + l]; g2 = sn[128 + l];
            g3 = sn[192 + l]; g4 = sn[256 + l]; g5 = sn[320 + l];
        }
        float cut = c0.y;
        float u0 = c0.z, u1 = c0.w, u2 = c1.x;
        float f0 = bf0 * cut, f1 = bf1 * cut, f2 = bf2 * cut;
        half2v rp[10] = { ash2(c1.y), ash2(c1.z), ash2(c1.w),
                          ash2(c2.x), ash2(c2.y), ash2(c2.z), ash2(c2.w),
                          ash2(c3.x), ash2(c3.y), ash2(c3.z) };
#pragma unroll
        for (int j = 0; j < 10; j++) {
            f0 = __builtin_amdgcn_fdot2(rp[j], wf0[j], f0, false);
            f1 = __builtin_amdgcn_fdot2(rp[j], wf1[j], f1, false);
            f2 = __builtin_amdgcn_fdot2(rp[j], wf2[j], f2, false);
        }
        float s0 = bup((unsigned short)h0);
        float s1 = bup((unsigned short)h1);
        float s2 = bup((unsigned short)h2);
        float v0 = bup((unsigned short)h3);
        float v1 = bup((unsigned short)h4);
        float v2 = bup((unsigned short)h5);
        float gg0 = f0 * s0, gg1 = f1 * s1;
        acc_s += f2 * s2;
        a0 += fmaf(v0, gg0, gg1 * u0);
        a1 += fmaf(v1, gg0, gg1 * u1);
        a2 += fmaf(v2, gg0, gg1 * u2);
    }

    size_t b64 = (size_t)n * 64, b192 = (size_t)n * 192;
    out0[b64 + l] = ns[b64 + l] + acc_s;
    out1[b192 + l] = nv[b192 + l] + a0;
    out1[b192 + 64 + l] = nv[b192 + 64 + l] + a1;
    out1[b192 + 128 + l] = nv[b192 + 128 + l] + a2;
}

extern "C" void kernel_launch(void* const* d_in, const int* in_sizes, int n_in,
                              void* d_out, int out_size, void* d_ws, size_t ws_size,
                              hipStream_t stream) {
    const float* ns    = (const float*)d_in[0];
    const float* nv    = (const float*)d_in[1];
    const int*   edge  = (const int*)d_in[2];
    const float* ediff = (const float*)d_in[3];
    const float* edist = (const float*)d_in[4];
    const float* W1    = (const float*)d_in[5];
    const float* b1    = (const float*)d_in[6];
    const float* W2    = (const float*)d_in[7];
    const float* b2    = (const float*)d_in[8];
    const float* Wf    = (const float*)d_in[9];
    const float* bfv   = (const float*)d_in[10];

    float* out0 = (float*)d_out;
    float* out1 = out0 + (size_t)N_NODES * 64;

    char* wsp = (char*)d_ws;
    float4* pack = (float4*)wsp;                    wsp += (size_t)N_EDGES * 64;
    unsigned short* snb = (unsigned short*)wsp;     wsp += (size_t)N_NODES * 384 * 2;
    unsigned short* W1t = (unsigned short*)wsp;     wsp += 64 * 64 * 2;
    unsigned short* W2t = (unsigned short*)wsp;     wsp += 192 * 64 * 2;
    unsigned int* Wfp = (unsigned int*)wsp;         wsp += 1920 * 4;
    int* counts  = (int*)wsp;
    int* offs    = counts + N_NODES;
    int* cursors = offs + (N_NODES + 1);
    int* bsum    = cursors + N_NODES;
    int* boff    = bsum + 256;

    wprep_kernel<<<48, 256, 0, stream>>>(W1, W2, Wf, W1t, W2t, Wfp);
    nv_convert_kernel<<<(N_NODES * 192 / 4 + 255) / 256, 256, 0, stream>>>(nv, snb, counts);
    node_mlp_kernel<<<(N_NODES + 63) / 64, 256, 0, stream>>>(ns, W1t, b1, W2t, b2, snb);
    hist_kernel<<<(N_EDGES + 255) / 256, 256, 0, stream>>>(edge, counts);
    scan_part1<<<NBLK, 256, 0, stream>>>(counts, bsum);
    scan_part2<<<1, 256, 0, stream>>>(bsum, boff);
    scan_part3<<<NBLK, 256, 0, stream>>>(counts, boff, offs, cursors);
    bucket_kernel<<<(N_EDGES + 255) / 256, 256, 0, stream>>>(edge, ediff, edist, cursors, pack);
    gather_kernel<<<N_NODES / 4, 256, 0, stream>>>(ns, nv, Wfp, bfv, snb, offs, pack,
                                                   out0, out1);
}

// Round 5
// 361.994 us; speedup vs baseline: 1.5330x; 1.2029x over previous
//
#include <hip/hip_runtime.h>
#include <hip/hip_bf16.h>
#include <math.h>

#define N_NODES 50000
#define N_EDGES 800000
#define NRAD 20
#define NBLK 196   // ceil(50000/256)

typedef short bf16x8 __attribute__((ext_vector_type(8)));
typedef float f32x4 __attribute__((ext_vector_type(4)));
typedef _Float16 half2v __attribute__((ext_vector_type(2)));
typedef int i32x16 __attribute__((ext_vector_type(16)));

__device__ __forceinline__ unsigned short f2b(float f) {
    union { __hip_bfloat16 h; unsigned short u; } cv;
    cv.h = __float2bfloat16(f);
    return cv.u;
}
__device__ __forceinline__ unsigned int packh2(float a, float b) {
    union { _Float16 h; unsigned short u; } A, B;
    A.h = (_Float16)a; B.h = (_Float16)b;
    return (unsigned int)A.u | ((unsigned int)B.u << 16);
}
__device__ __forceinline__ half2v ash2u(unsigned int x) {
    union { unsigned int u; half2v h; } u; u.u = x; return u.h;
}
__device__ __forceinline__ f32x4 mfma16(bf16x8 a, bf16x8 b, f32x4 c) {
    return __builtin_amdgcn_mfma_f32_16x16x32_bf16(a, b, c, 0, 0, 0);
}

// Fused: zero counts + nv f32->bf16 into snb[n][lane][3..5] + weight prep (tail blocks).
// snb layout: per node 768B = 64 lanes x 6 ushort {s0,s1,s2,v0,v1,v2}.
__global__ __launch_bounds__(256) void prep_kernel(
    const float* __restrict__ nv, unsigned short* __restrict__ snb, int* __restrict__ counts,
    const float* __restrict__ W1, const float* __restrict__ W2, const float* __restrict__ Wf,
    unsigned short* __restrict__ W1t, unsigned short* __restrict__ W2t,
    unsigned int* __restrict__ Wfp) {
    int b = blockIdx.x;
    if (b < 12500) {
        int i = b * 256 + threadIdx.x;
        if (i < N_NODES) counts[i] = 0;
        if (i < N_NODES * 64) {
            int n = i >> 6, l = i & 63;
            float v0 = nv[(size_t)n * 192 + l];
            float v1 = nv[(size_t)n * 192 + 64 + l];
            float v2 = nv[(size_t)n * 192 + 128 + l];
            char* p = (char*)snb + (size_t)n * 768 + l * 12;
            *(unsigned short*)(p + 6) = f2b(v0);
            *(unsigned int*)(p + 8) = (unsigned int)f2b(v1) | ((unsigned int)f2b(v2) << 16);
        }
    } else {
        int i = (b - 12500) * 256 + threadIdx.x;
        if (i < 64 * 64) { int n = i >> 6, k = i & 63; W1t[i] = f2b(W1[k * 64 + n]); }
        if (i < 192 * 64) { int n = i >> 6, k = i & 63; W2t[i] = f2b(W2[k * 192 + n]); }
        if (i < 3 * 10 * 64) {
            int ch = i / 640, rem = i % 640, j = rem >> 6, l = rem & 63;
            Wfp[i] = packh2(Wf[(2 * j) * 192 + ch * 64 + l],
                            Wf[(2 * j + 1) * 192 + ch * 64 + l]);
        }
    }
}

// MFMA MLP: block = 256 thr = 4 waves, 64 nodes. Wave w owns rows [16w,16w+16).
__global__ __launch_bounds__(256) void node_mlp_kernel(
    const float* __restrict__ ns, const unsigned short* __restrict__ W1t,
    const float* __restrict__ b1, const unsigned short* __restrict__ W2t,
    const float* __restrict__ b2, unsigned short* __restrict__ snb) {
    __shared__ unsigned short H[64 * 72];
    __shared__ unsigned short O[64 * 200];
    int t = threadIdx.x;
    int lane = t & 63;
    int w = t >> 6;
    int c15 = lane & 15;
    int quad = lane >> 4;
    int base = blockIdx.x * 64;

    int node = base + 16 * w + c15;
    if (node >= N_NODES) node = N_NODES - 1;

    bf16x8 a0, a1;
    {
        const float* xr = ns + (size_t)node * 64 + quad * 8;
        float4 p0 = *(const float4*)xr;
        float4 p1 = *(const float4*)(xr + 4);
        float4 p2 = *(const float4*)(xr + 32);
        float4 p3 = *(const float4*)(xr + 36);
        a0[0] = (short)f2b(p0.x); a0[1] = (short)f2b(p0.y);
        a0[2] = (short)f2b(p0.z); a0[3] = (short)f2b(p0.w);
        a0[4] = (short)f2b(p1.x); a0[5] = (short)f2b(p1.y);
        a0[6] = (short)f2b(p1.z); a0[7] = (short)f2b(p1.w);
        a1[0] = (short)f2b(p2.x); a1[1] = (short)f2b(p2.y);
        a1[2] = (short)f2b(p2.z); a1[3] = (short)f2b(p2.w);
        a1[4] = (short)f2b(p3.x); a1[5] = (short)f2b(p3.y);
        a1[6] = (short)f2b(p3.z); a1[7] = (short)f2b(p3.w);
    }

#pragma unroll
    for (int nt = 0; nt < 4; nt++) {
        float bc = b1[nt * 16 + c15];
        f32x4 acc = {bc, bc, bc, bc};
        bf16x8 w0 = *(const bf16x8*)(W1t + (nt * 16 + c15) * 64 + quad * 8);
        bf16x8 w1 = *(const bf16x8*)(W1t + (nt * 16 + c15) * 64 + 32 + quad * 8);
        acc = mfma16(a0, w0, acc);
        acc = mfma16(a1, w1, acc);
#pragma unroll
        for (int r = 0; r < 4; r++) {
            float v = acc[r];
            v = v / (1.0f + __expf(-v));
            H[(16 * w + quad * 4 + r) * 72 + nt * 16 + c15] = f2b(v);
        }
    }

    bf16x8 h0 = *(const bf16x8*)(H + (16 * w + c15) * 72 + quad * 8);
    bf16x8 h1 = *(const bf16x8*)(H + (16 * w + c15) * 72 + 32 + quad * 8);

#pragma unroll
    for (int nt = 0; nt < 12; nt++) {
        float bc = b2[nt * 16 + c15];
        f32x4 acc = {bc, bc, bc, bc};
        bf16x8 w0 = *(const bf16x8*)(W2t + (nt * 16 + c15) * 64 + quad * 8);
        bf16x8 w1 = *(const bf16x8*)(W2t + (nt * 16 + c15) * 64 + 32 + quad * 8);
        acc = mfma16(h0, w0, acc);
        acc = mfma16(h1, w1, acc);
#pragma unroll
        for (int r = 0; r < 4; r++)
            O[(16 * w + quad * 4 + r) * 200 + nt * 16 + c15] = f2b(acc[r]);
    }
    __syncthreads();

    int nb = min(64, N_NODES - base);
    for (int idx = t; idx < nb * 64; idx += 256) {
        int row = idx >> 6, ll = idx & 63;
        unsigned short o0 = O[row * 200 + ll];
        unsigned short o1 = O[row * 200 + 64 + ll];
        unsigned short o2 = O[row * 200 + 128 + ll];
        char* p = (char*)snb + (size_t)(base + row) * 768 + ll * 12;
        *(unsigned int*)p = (unsigned int)o0 | ((unsigned int)o1 << 16);
        *(unsigned short*)(p + 4) = o2;
    }
}

__global__ void hist_kernel(const int* __restrict__ edge, int* __restrict__ counts) {
    int e = blockIdx.x * blockDim.x + threadIdx.x;
    if (e < N_EDGES) atomicAdd(&counts[edge[2 * e]], 1);
}

__global__ __launch_bounds__(256) void scan_part1(const int* __restrict__ counts,
                                                  int* __restrict__ bsum) {
    __shared__ int red[256];
    int t = threadIdx.x, i = blockIdx.x * 256 + t;
    red[t] = (i < N_NODES) ? counts[i] : 0;
    __syncthreads();
    for (int s = 128; s > 0; s >>= 1) {
        if (t < s) red[t] += red[t + s];
        __syncthreads();
    }
    if (t == 0) bsum[blockIdx.x] = red[0];
}

__global__ __launch_bounds__(256) void scan_part2(const int* __restrict__ bsum,
                                                  int* __restrict__ boff) {
    __shared__ int s[256];
    int t = threadIdx.x;
    s[t] = (t < NBLK) ? bsum[t] : 0;
    __syncthreads();
    for (int off = 1; off < 256; off <<= 1) {
        int v = (t >= off) ? s[t - off] : 0;
        __syncthreads();
        s[t] += v;
        __syncthreads();
    }
    boff[t] = (t == 0) ? 0 : s[t - 1];
}

__global__ __launch_bounds__(256) void scan_part3(const int* __restrict__ counts,
                                                  const int* __restrict__ boff,
                                                  int* __restrict__ offs,
                                                  int* __restrict__ cursors) {
    __shared__ int s[256];
    int t = threadIdx.x, b = blockIdx.x, i = b * 256 + t;
    int v = (i < N_NODES) ? counts[i] : 0;
    s[t] = v;
    __syncthreads();
    for (int off = 1; off < 256; off <<= 1) {
        int u = (t >= off) ? s[t - off] : 0;
        __syncthreads();
        s[t] += u;
        __syncthreads();
    }
    int excl = s[t] - v + boff[b];
    if (i < N_NODES) {
        offs[i] = excl;
        cursors[i] = excl;
    }
    if (i == N_NODES - 1) offs[N_NODES] = excl + v;
}

// Bucket + per-edge scalar precompute. 64B struct, dst-sorted:
// words: [0]=src, [1]=cut, [2..4]=u0,u1,u2, [5..14]=rp0..rp9 (f16 pairs), [15]=0
__global__ __launch_bounds__(256) void bucket_kernel(
    const int* __restrict__ edge, const float* __restrict__ ediff,
    const float* __restrict__ edist, int* __restrict__ cursors,
    float4* __restrict__ pack) {
    int e = blockIdx.x * blockDim.x + threadIdx.x;
    if (e >= N_EDGES) return;
    int dst = edge[2 * e];
    int src = edge[2 * e + 1];
    int pos = atomicAdd(&cursors[dst], 1);

    float dist = edist[e];
    float d0 = ediff[3 * e], d1 = ediff[3 * e + 1], d2 = ediff[3 * e + 2];
    float inv = __builtin_amdgcn_rcpf(dist);
    float x = dist * (3.14159265358979323846f / 5.0f);
    float s1 = __sinf(x);
    float c1 = __cosf(x);
    float cut = (dist < 5.0f) ? 0.5f * (c1 + 1.0f) : 0.0f;
    float ic = inv * cut;
    float t2 = 2.0f * c1;
    float r[NRAD];
    float sn = s1, sp = 0.0f;
#pragma unroll
    for (int k = 0; k < NRAD; k++) {
        r[k] = sn * ic;
        float nx = t2 * sn - sp;
        sp = sn;
        sn = nx;
    }
    unsigned int rp[10];
#pragma unroll
    for (int j = 0; j < 10; j++) rp[j] = packh2(r[2 * j], r[2 * j + 1]);

    float4* P = pack + (size_t)pos * 4;
    P[0] = make_float4(__int_as_float(src), cut, d0 * inv, d1 * inv);
    P[1] = make_float4(d2 * inv, __uint_as_float(rp[0]), __uint_as_float(rp[1]),
                       __uint_as_float(rp[2]));
    P[2] = make_float4(__uint_as_float(rp[3]), __uint_as_float(rp[4]),
                       __uint_as_float(rp[5]), __uint_as_float(rp[6]));
    P[3] = make_float4(__uint_as_float(rp[7]), __uint_as_float(rp[8]),
                       __uint_as_float(rp[9]), 0.0f);
}

// Persistent waves, grid-stride over nodes. Pack entries via s_load_dwordx16
// (wave-uniform), snb via single dwordx3/lane, both software-pipelined.
__global__ __launch_bounds__(256) void gather_kernel(
    const float* __restrict__ ns, const float* __restrict__ nv,
    const unsigned int* __restrict__ Wfp, const float* __restrict__ bfv,
    const unsigned short* __restrict__ snb, const int* __restrict__ offs,
    const float4* __restrict__ pack, float* __restrict__ out0, float* __restrict__ out1) {
    int t = threadIdx.x;
    int l = t & 63;
    int wid = __builtin_amdgcn_readfirstlane((int)(blockIdx.x * 4 + (t >> 6)));
    int W = gridDim.x * 4;

    half2v wf0[10], wf1[10], wf2[10];
#pragma unroll
    for (int j = 0; j < 10; j++) {
        wf0[j] = ash2u(Wfp[j * 64 + l]);
        wf1[j] = ash2u(Wfp[640 + j * 64 + l]);
        wf2[j] = ash2u(Wfp[1280 + j * 64 + l]);
    }
    float bf0 = bfv[l], bf1 = bfv[64 + l], bf2 = bfv[128 + l];

    const char* packb = (const char*)pack;
    const char* snbb = (const char*)snb;

    for (int n = wid; n < N_NODES; n += W) {
        int start = __builtin_amdgcn_readfirstlane(offs[n]);
        int end = __builtin_amdgcn_readfirstlane(offs[n + 1]);
        float acc_s = 0.0f, a0 = 0.0f, a1 = 0.0f, a2 = 0.0f;

        if (start < end) {
            i32x16 A;
            unsigned long long pa =
                (unsigned long long)packb + (unsigned long long)(unsigned)start * 64ull;
            asm volatile("s_load_dwordx16 %0, %1, 0x0" : "=s"(A) : "s"(pa));
            asm volatile("s_waitcnt lgkmcnt(0)" : "+s"(A));
            i32x16 B = A;
            uint3 gA = *(const uint3*)(snbb + (size_t)(unsigned)A[0] * 768 + l * 12);
            if (start + 1 < end)
                asm volatile("s_load_dwordx16 %0, %1, 0x0" : "=s"(B) : "s"(pa + 64ull));

            for (int i = start; i < end; i++) {
                float cut = __int_as_float(A[1]);
                float u0 = __int_as_float(A[2]);
                float u1 = __int_as_float(A[3]);
                float u2 = __int_as_float(A[4]);
                float f0 = bf0 * cut, f1 = bf1 * cut, f2 = bf2 * cut;
#pragma unroll
                for (int j = 0; j < 10; j++) {
                    half2v rp = ash2u((unsigned)A[5 + j]);
                    f0 = __builtin_amdgcn_fdot2(rp, wf0[j], f0, false);
                    f1 = __builtin_amdgcn_fdot2(rp, wf1[j], f1, false);
                    f2 = __builtin_amdgcn_fdot2(rp, wf2[j], f2, false);
                }
                uint3 gN = gA;
                if (i + 1 < end) {
                    asm volatile("s_waitcnt lgkmcnt(0)" : "+s"(B));
                    gN = *(const uint3*)(snbb + (size_t)(unsigned)B[0] * 768 + l * 12);
                }
                float s0 = __uint_as_float(gA.x << 16);
                float s1 = __uint_as_float(gA.x & 0xffff0000u);
                float s2 = __uint_as_float(gA.y << 16);
                float v0 = __uint_as_float(gA.y & 0xffff0000u);
                float v1 = __uint_as_float(gA.z << 16);
                float v2 = __uint_as_float(gA.z & 0xffff0000u);
                float gg0 = f0 * s0, gg1 = f1 * s1;
                acc_s += f2 * s2;
                a0 += fmaf(v0, gg0, gg1 * u0);
                a1 += fmaf(v1, gg0, gg1 * u1);
                a2 += fmaf(v2, gg0, gg1 * u2);
                A = B;
                gA = gN;
                if (i + 2 < end) {
                    unsigned long long pn =
                        (unsigned long long)packb + (unsigned long long)(unsigned)(i + 2) * 64ull;
                    asm volatile("s_load_dwordx16 %0, %1, 0x0" : "=s"(B) : "s"(pn));
                }
            }
        }

        size_t b64 = (size_t)n * 64 + l, b192 = (size_t)n * 192 + l;
        out0[b64] = ns[b64] + acc_s;
        out1[b192] = nv[b192] + a0;
        out1[b192 + 64] = nv[b192 + 64] + a1;
        out1[b192 + 128] = nv[b192 + 128] + a2;
    }
}

extern "C" void kernel_launch(void* const* d_in, const int* in_sizes, int n_in,
                              void* d_out, int out_size, void* d_ws, size_t ws_size,
                              hipStream_t stream) {
    const float* ns    = (const float*)d_in[0];
    const float* nv    = (const float*)d_in[1];
    const int*   edge  = (const int*)d_in[2];
    const float* ediff = (const float*)d_in[3];
    const float* edist = (const float*)d_in[4];
    const float* W1    = (const float*)d_in[5];
    const float* b1    = (const float*)d_in[6];
    const float* W2    = (const float*)d_in[7];
    const float* b2    = (const float*)d_in[8];
    const float* Wf    = (const float*)d_in[9];
    const float* bfv   = (const float*)d_in[10];

    float* out0 = (float*)d_out;
    float* out1 = out0 + (size_t)N_NODES * 64;

    char* wsp = (char*)d_ws;
    float4* pack = (float4*)wsp;                    wsp += (size_t)N_EDGES * 64;
    unsigned short* snb = (unsigned short*)wsp;     wsp += (size_t)N_NODES * 768;
    unsigned short* W1t = (unsigned short*)wsp;     wsp += 64 * 64 * 2;
    unsigned short* W2t = (unsigned short*)wsp;     wsp += 192 * 64 * 2;
    unsigned int* Wfp = (unsigned int*)wsp;         wsp += 1920 * 4;
    int* counts  = (int*)wsp;
    int* offs    = counts + N_NODES;
    int* cursors = offs + (N_NODES + 1);
    int* bsum    = cursors + N_NODES;
    int* boff    = bsum + 256;

    prep_kernel<<<12548, 256, 0, stream>>>(nv, snb, counts, W1, W2, Wf, W1t, W2t, Wfp);
    node_mlp_kernel<<<(N_NODES + 63) / 64, 256, 0, stream>>>(ns, W1t, b1, W2t, b2, snb);
    hist_kernel<<<(N_EDGES + 255) / 256, 256, 0, stream>>>(edge, counts);
    scan_part1<<<NBLK, 256, 0, stream>>>(counts, bsum);
    scan_part2<<<1, 256, 0, stream>>>(bsum, boff);
    scan_part3<<<NBLK, 256, 0, stream>>>(counts, boff, offs, cursors);
    bucket_kernel<<<(N_EDGES + 255) / 256, 256, 0, stream>>>(edge, ediff, edist, cursors, pack);
    gather_kernel<<<2048, 256, 0, stream>>>(ns, nv, Wfp, bfv, snb, offs, pack, out0, out1);
}